// Round 15
// baseline (77.553 us; speedup 1.0000x reference)
//
#include <hip/hip_runtime.h>

// Problem constants (from reference setup_inputs)
#define BB 4096   // batch
#define SS 256    // sequence length
#define FF 64     // features
#define GG 9      // 3*U gate width

#define NEG_LOG2E -1.4426950408889634f
#define TWO_LOG2E  2.8853900817779268f

typedef float f2 __attribute__((ext_vector_type(2)));

#if __has_builtin(__builtin_amdgcn_exp2f)
__device__ __forceinline__ float fast_exp2(float x) { return __builtin_amdgcn_exp2f(x); }
#else
__device__ __forceinline__ float fast_exp2(float x) { return exp2f(x); }
#endif
#if __has_builtin(__builtin_amdgcn_rcpf)
__device__ __forceinline__ float fast_rcp(float x) { return __builtin_amdgcn_rcpf(x); }
#else
__device__ __forceinline__ float fast_rcp(float x) { return 1.0f / x; }
#endif

// DPP helper: quad_perm (CTRL<0x100) and row ops (row_ror:N = 0x120+N).
template <int CTRL>
__device__ __forceinline__ float dpp_f(float v) {
  return __int_as_float(
      __builtin_amdgcn_mov_dpp(__float_as_int(v), CTRL, 0xF, 0xF, true));
}

// -----------------------------------------------------------------------------
// Fully fused GRU — R15: feature-major ROLE decomposition kills the butterfly.
// R14 confirmed DPP ops cost ~4-5cy each at 1 wave/SIMD (removing 12 saved
// 6.3us). R14 still used 27 DPP/step. R15 restructures: lane (quad q, role u)
// accumulates ONLY its role's 3 gate columns {z_u, r_u, h_u} over features
// 16q..16q+15. Full sums then need reducing only across the 4 same-role lanes
// {l, l+4, l+8, l+12} = row_ror:4 + row_ror:8 rotate-accumulate (role-
// preserving; primitive verified absmax-0 in R12/R14). Butterfly (18 DPP) and
// select (6 cndmask) GONE: 27 -> 9 DPP/step. Projection: 32 FMA instrs over
// 16 features (f2-packed z,r + scalar h). Loads: 4 float4/lane/step; quad
// lanes read identical addresses (HW broadcast; traffic unchanged 256B/chain).
// Ring depth 4 (64 buffer VGPRs, ~150 total — under R6's collapse regime).
// Bias Q=1/4 (exact); z/r recurrent-bias fold (R11+ verified). Gate chain
// byte-identical to the absmax-0 lineage.
// -----------------------------------------------------------------------------
__global__ __launch_bounds__(64, 1) void fused_gru_kernel(
    const float* __restrict__ x,           // [B,S,F]
    const float* __restrict__ kernel_w,    // [F,9]
    const float* __restrict__ rec_kernel,  // [3,9]
    const float* __restrict__ bias,        // [2,9]
    const float* __restrict__ dense_w,     // [3,10]
    const float* __restrict__ dense_b,     // [10]
    float* __restrict__ out)               // [B,10]
{
  const int lane = threadIdx.x;        // 0..63
  const int l16  = lane & 15;          // slot within the chain's 16-lane row
  const int u    = l16 & 3;            // gate-unit role within the quad
  const int uc   = (u < 3) ? u : 2;    // role-3 lanes: duplicate unit 2 (benign)
  const int q    = l16 >> 2;           // feature segment (16q .. 16q+15)
  const int c    = blockIdx.x * 4 + (lane >> 4);   // chain (batch) id

  // ---- input-projection weights: this lane's 3 role columns x 16 features
  // (pre-scaled; z,r packed as f2, h scalar)
  f2 wzr[16];
  float wh_[16];
#pragma unroll
  for (int e = 0; e < 16; ++e) {
    const float* kw = kernel_w + (16 * q + e) * GG;
    wzr[e] = (f2){kw[uc] * NEG_LOG2E, kw[3 + uc] * NEG_LOG2E};
    wh_[e] = kw[6 + uc] * TWO_LOG2E;
  }

  // bias (z/r: +recurrent bias folded — exact), pre-scaled, QUARTERED
  // (4-lane same-role reduce restores exactly 1x).
  const float Q = 0.25f;
  const f2 bzr = {(bias[uc] + bias[GG + uc]) * NEG_LOG2E * Q,
                  (bias[3 + uc] + bias[GG + 3 + uc]) * NEG_LOG2E * Q};
  const float bh = bias[6 + uc] * TWO_LOG2E * Q;

  // recurrent weights for this lane's unit (pre-scaled); h-gate recurrent
  // bias stays separate (inside the r-multiplied term).
  float wz[3], wr[3], wh[3];
#pragma unroll
  for (int hh = 0; hh < 3; ++hh) {
    wz[hh] = rec_kernel[hh * GG + uc]     * NEG_LOG2E;
    wr[hh] = rec_kernel[hh * GG + 3 + uc] * NEG_LOG2E;
    wh[hh] = rec_kernel[hh * GG + 6 + uc] * TWO_LOG2E;
  }
  const float rbh = bias[GG + 6 + uc] * TWO_LOG2E;

  float h0 = 0.0f, h1 = 0.0f, h2 = 0.0f, hprev = 0.0f;

  // per-lane x pointer: chain c, features 16q..16q+15 (4 float4s per step;
  // the 4 lanes of a quad read identical addresses -> HW broadcast).
  const float* pX = x + (size_t)c * SS * FF + 16 * q;

  // depth-4 register ring (64 VGPRs), named buffers, static indexing
  float4 X0[4], X1[4], X2[4], X3[4];
  auto ldt = [&](float4 (&R)[4], int s) {
    const float* p = pX + (size_t)s * FF;
    R[0] = *reinterpret_cast<const float4*>(p);
    R[1] = *reinterpret_cast<const float4*>(p + 4);
    R[2] = *reinterpret_cast<const float4*>(p + 8);
    R[3] = *reinterpret_cast<const float4*>(p + 12);
  };

  auto step = [&](const float4 (&V)[4]) {
    // role-column projection over 16 features: 16 pk-FMA + 16 FMA
    f2 azr = bzr;
    float sh = bh;
#pragma unroll
    for (int j = 0; j < 4; ++j) {
      const float4 v = V[j];
      const int e = j * 4;
      azr = v.x * wzr[e + 0] + azr; sh = fmaf(v.x, wh_[e + 0], sh);
      azr = v.y * wzr[e + 1] + azr; sh = fmaf(v.y, wh_[e + 1], sh);
      azr = v.z * wzr[e + 2] + azr; sh = fmaf(v.z, wh_[e + 2], sh);
      azr = v.w * wzr[e + 3] + azr; sh = fmaf(v.w, wh_[e + 3], sh);
    }

    // 4-lane same-role reduce: rotate-accumulate over {l, l+4, l+8, l+12}
    // (row_ror:4 / row_ror:8 preserve lane&3 -> role alignment; verified).
    float az = azr.x, ar = azr.y;
    az += dpp_f<0x124>(az); ar += dpp_f<0x124>(ar); sh += dpp_f<0x124>(sh);
    az += dpp_f<0x128>(az); ar += dpp_f<0x128>(ar); sh += dpp_f<0x128>(sh);

    // gate chain (absmax-0 verified math; b0+b1 already inside az/ar)
    const float iz = fmaf(h2, wz[2], fmaf(h1, wz[1], fmaf(h0, wz[0], az)));
    const float ir = fmaf(h2, wr[2], fmaf(h1, wr[1], fmaf(h0, wr[0], ar)));
    const float ih = fmaf(h2, wh[2], fmaf(h1, wh[1], fmaf(h0, wh[0], rbh)));
    const float z = fast_rcp(1.0f + fast_exp2(iz));
    const float r = fast_rcp(1.0f + fast_exp2(ir));
    const float t = fmaf(-2.0f, fast_rcp(1.0f + fast_exp2(fmaf(r, ih, sh))), 1.0f);
    const float hn = fmaf(z, hprev - t, t);
    hprev = hn;
    h0 = dpp_f<0x00>(hn);   // quad_perm [0,0,0,0]
    h1 = dpp_f<0x55>(hn);   // quad_perm [1,1,1,1]
    h2 = dpp_f<0xAA>(hn);   // quad_perm [2,2,2,2]
  };

  auto clampi = [](int sn) { return (sn < SS) ? sn : (SS - 1); };

  ldt(X0, 0); ldt(X1, 1); ldt(X2, 2); ldt(X3, 3);
  for (int sg = 0; sg < SS; sg += 4) {
    step(X0); ldt(X0, clampi(sg + 4));
    step(X1); ldt(X1, clampi(sg + 5));
    step(X2); ldt(X2, clampi(sg + 6));
    step(X3); ldt(X3, clampi(sg + 7));
  }

  // Dense (3 -> 10) + softmax; quad 0 of each chain row writes (h0..h2 are
  // quad-uniform after the broadcasts).
  if (l16 < 4) {
    float lg[10];
#pragma unroll
    for (int j = 0; j < 10; ++j)
      lg[j] = dense_b[j] + h0 * dense_w[j] + h1 * dense_w[10 + j] + h2 * dense_w[20 + j];
    float m = lg[0];
#pragma unroll
    for (int j = 1; j < 10; ++j) m = fmaxf(m, lg[j]);
    float e[10];
    float ssum = 0.0f;
#pragma unroll
    for (int j = 0; j < 10; ++j) {
      e[j] = fast_exp2(1.4426950408889634f * (lg[j] - m));
      ssum += e[j];
    }
    const float inv = fast_rcp(ssum);
#pragma unroll
    for (int j = u; j < 10; j += 4) out[(size_t)c * 10 + j] = e[j] * inv;
  }
}

extern "C" void kernel_launch(void* const* d_in, const int* in_sizes, int n_in,
                              void* d_out, int out_size, void* d_ws, size_t ws_size,
                              hipStream_t stream) {
  const float* x      = (const float*)d_in[0];  // [4096,256,64]
  const float* kern   = (const float*)d_in[1];  // [64,9]
  const float* rkern  = (const float*)d_in[2];  // [3,9]
  const float* bias   = (const float*)d_in[3];  // [2,9]
  const float* dw     = (const float*)d_in[4];  // [3,10]
  const float* db     = (const float*)d_in[5];  // [10]
  float* out = (float*)d_out;

  // 4 chains x 16 lanes per 64-thread block; 1024 blocks -> 1 wave per SIMD
  // on all 1024 SIMDs.
  fused_gru_kernel<<<BB / 4, 64, 0, stream>>>(x, kern, rkern, bias, dw, db, out);
}

// Round 16
// 64.340 us; speedup vs baseline: 1.2054x; 1.2054x over previous
//
#include <hip/hip_runtime.h>

// Problem constants (from reference setup_inputs)
#define BB 4096   // batch
#define SS 256    // sequence length
#define FF 64     // features
#define GG 9      // 3*U gate width
#define TT 16     // steps per producer/consumer tile
#define NT (SS / TT)

#define NEG_LOG2E -1.4426950408889634f
#define TWO_LOG2E  2.8853900817779268f

typedef float f2 __attribute__((ext_vector_type(2)));

#if __has_builtin(__builtin_amdgcn_exp2f)
__device__ __forceinline__ float fast_exp2(float x) { return __builtin_amdgcn_exp2f(x); }
#else
__device__ __forceinline__ float fast_exp2(float x) { return exp2f(x); }
#endif
#if __has_builtin(__builtin_amdgcn_rcpf)
__device__ __forceinline__ float fast_rcp(float x) { return __builtin_amdgcn_rcpf(x); }
#else
__device__ __forceinline__ float fast_rcp(float x) { return 1.0f / x; }
#endif

// DPP helper: quad_perm (CTRL<0x100) and row ops (row_ror:N = 0x120+N).
template <int CTRL>
__device__ __forceinline__ float dpp_f(float v) {
  return __int_as_float(
      __builtin_amdgcn_mov_dpp(__float_as_int(v), CTRL, 0xF, 0xF, true));
}

// -----------------------------------------------------------------------------
// Fully fused GRU — R16: producer/consumer wave specialization.
// R14 (champion, 54.7us): ~460cy/step, issue ~220cy, serial gate ~100cy; the
// stall gap is fillable only by TLP (R10/R11: not latency/ordering; R12/R15:
// wider lanes cost more than TLP pays). R16 splits the work across 2 waves
// per block (4 chains): wave 0 = R14's proj+butterfly+select+ror VERBATIM,
// writing (az,ar,sh)/(chain,unit,step) into a double-buffered LDS tile;
// wave 1 = the serial gate chain only (3 LDS reads + ~23 VALU + 3 quad-DPP
// per step). 1024 blocks x 2 waves = 2048 waves = 2/SIMD: producer issue
// fills consumer dependency bubbles. Textbook alternating double-buffer,
// one __syncthreads() per tile. Math byte-identical to the absmax-0 lineage.
// LDS reads/writes hit 12 distinct banks (verified by hand) -> conflict-free.
// -----------------------------------------------------------------------------
__global__ __launch_bounds__(128, 2) void fused_gru_kernel(
    const float* __restrict__ x,           // [B,S,F]
    const float* __restrict__ kernel_w,    // [F,9]
    const float* __restrict__ rec_kernel,  // [3,9]
    const float* __restrict__ bias,        // [2,9]
    const float* __restrict__ dense_w,     // [3,10]
    const float* __restrict__ dense_b,     // [10]
    float* __restrict__ out)               // [B,10]
{
  __shared__ float lds[2][TT][4][12];  // [buf][step][chain][unit*3 + {az,ar,sh}]

  const int tid = threadIdx.x;         // 0..127
  const int wid = tid >> 6;            // 0 = producer wave, 1 = consumer wave
  const int l   = tid & 63;
  const int l16 = l & 15;              // slot within the chain's 16-lane row
  const int u   = l16 & 3;             // gate-unit role within the quad
  const int uc  = (u < 3) ? u : 2;     // role-3 lanes duplicate unit 2 (benign)
  const int row = l >> 4;              // chain row 0..3
  const int c   = blockIdx.x * 4 + row;

  // ---------------- producer state (wave 0; R14 verbatim) ----------------
  f2 w01[4], w23[4], w45[4], w67[4];
  float w8[4];
#pragma unroll
  for (int e = 0; e < 4; ++e) {
    const float* kw = kernel_w + (l16 * 4 + e) * GG;
    w01[e] = (f2){kw[0] * NEG_LOG2E, kw[1] * NEG_LOG2E};
    w23[e] = (f2){kw[2] * NEG_LOG2E, kw[3] * NEG_LOG2E};
    w45[e] = (f2){kw[4] * NEG_LOG2E, kw[5] * NEG_LOG2E};
    w67[e] = (f2){kw[6] * TWO_LOG2E, kw[7] * TWO_LOG2E};
    w8[e]  = kw[8] * TWO_LOG2E;
  }
  const float Q = 0.0625f;
  const f2 b01q = {(bias[0] + bias[GG + 0]) * NEG_LOG2E * Q,
                   (bias[1] + bias[GG + 1]) * NEG_LOG2E * Q};
  const f2 b23q = {(bias[2] + bias[GG + 2]) * NEG_LOG2E * Q,
                   (bias[3] + bias[GG + 3]) * NEG_LOG2E * Q};
  const f2 b45q = {(bias[4] + bias[GG + 4]) * NEG_LOG2E * Q,
                   (bias[5] + bias[GG + 5]) * NEG_LOG2E * Q};
  const f2 b67q = {bias[6] * TWO_LOG2E * Q, bias[7] * TWO_LOG2E * Q};
  const float b8q = bias[8] * TWO_LOG2E * Q;

  const float4* pc = reinterpret_cast<const float4*>(x) + (size_t)c * SS * 16 + l16;
  float4 X0, X1, X2, X3, X4, X5, X6, X7;  // depth-8 ring, static names
  auto pf = [&](int sn) -> float4 {
    sn = (sn < SS) ? sn : (SS - 1);
    return pc[(size_t)sn * 16];
  };

  auto produce_step = [&](const float4 v, int s) {
    f2 a01 = b01q, a23 = b23q, a45 = b45q, a67 = b67q;
    float a8 = b8q;
    a01 = v.x * w01[0] + a01; a23 = v.x * w23[0] + a23;
    a45 = v.x * w45[0] + a45; a67 = v.x * w67[0] + a67;
    a8 = fmaf(v.x, w8[0], a8);
    a01 = v.y * w01[1] + a01; a23 = v.y * w23[1] + a23;
    a45 = v.y * w45[1] + a45; a67 = v.y * w67[1] + a67;
    a8 = fmaf(v.y, w8[1], a8);
    a01 = v.z * w01[2] + a01; a23 = v.z * w23[2] + a23;
    a45 = v.z * w45[2] + a45; a67 = v.z * w67[2] + a67;
    a8 = fmaf(v.z, w8[2], a8);
    a01 = v.w * w01[3] + a01; a23 = v.w * w23[3] + a23;
    a45 = v.w * w45[3] + a45; a67 = v.w * w67[3] + a67;
    a8 = fmaf(v.w, w8[3], a8);

    float s0 = a01.x, s1 = a01.y, s2 = a23.x, s3 = a23.y, s4 = a45.x,
          s5 = a45.y, s6 = a67.x, s7 = a67.y, s8 = a8;
    s0 += dpp_f<0xB1>(s0); s1 += dpp_f<0xB1>(s1); s2 += dpp_f<0xB1>(s2);
    s3 += dpp_f<0xB1>(s3); s4 += dpp_f<0xB1>(s4); s5 += dpp_f<0xB1>(s5);
    s6 += dpp_f<0xB1>(s6); s7 += dpp_f<0xB1>(s7); s8 += dpp_f<0xB1>(s8);
    s0 += dpp_f<0x4E>(s0); s1 += dpp_f<0x4E>(s1); s2 += dpp_f<0x4E>(s2);
    s3 += dpp_f<0x4E>(s3); s4 += dpp_f<0x4E>(s4); s5 += dpp_f<0x4E>(s5);
    s6 += dpp_f<0x4E>(s6); s7 += dpp_f<0x4E>(s7); s8 += dpp_f<0x4E>(s8);

    float az = (u == 0) ? s0 : ((u == 1) ? s1 : s2);
    float ar = (u == 0) ? s3 : ((u == 1) ? s4 : s5);
    float sh = (u == 0) ? s6 : ((u == 1) ? s7 : s8);
    az += dpp_f<0x124>(az); ar += dpp_f<0x124>(ar); sh += dpp_f<0x124>(sh);
    az += dpp_f<0x128>(az); ar += dpp_f<0x128>(ar); sh += dpp_f<0x128>(sh);

    // lanes l16=0,1,2 of each chain row publish unit l16's three args
    if (l16 < 3) {
      float* p = &lds[(s >> 4) & 1][s & 15][row][l16 * 3];
      p[0] = az; p[1] = ar; p[2] = sh;
    }
  };

  auto prod8 = [&](int sb) {
    produce_step(X0, sb + 0); X0 = pf(sb + 8);
    produce_step(X1, sb + 1); X1 = pf(sb + 9);
    produce_step(X2, sb + 2); X2 = pf(sb + 10);
    produce_step(X3, sb + 3); X3 = pf(sb + 11);
    produce_step(X4, sb + 4); X4 = pf(sb + 12);
    produce_step(X5, sb + 5); X5 = pf(sb + 13);
    produce_step(X6, sb + 6); X6 = pf(sb + 14);
    produce_step(X7, sb + 7); X7 = pf(sb + 15);
  };

  // ---------------- consumer state (wave 1; R14 gate verbatim) ------------
  float wz[3], wr[3], wh[3];
#pragma unroll
  for (int hh = 0; hh < 3; ++hh) {
    wz[hh] = rec_kernel[hh * GG + uc]     * NEG_LOG2E;
    wr[hh] = rec_kernel[hh * GG + 3 + uc] * NEG_LOG2E;
    wh[hh] = rec_kernel[hh * GG + 6 + uc] * TWO_LOG2E;
  }
  const float rbh = bias[GG + 6 + uc] * TWO_LOG2E;
  float h0 = 0.0f, h1 = 0.0f, h2 = 0.0f, hprev = 0.0f;

  auto gate = [&](float az, float ar, float sh) {
    const float iz = fmaf(h2, wz[2], fmaf(h1, wz[1], fmaf(h0, wz[0], az)));
    const float ir = fmaf(h2, wr[2], fmaf(h1, wr[1], fmaf(h0, wr[0], ar)));
    const float ih = fmaf(h2, wh[2], fmaf(h1, wh[1], fmaf(h0, wh[0], rbh)));
    const float z = fast_rcp(1.0f + fast_exp2(iz));
    const float r = fast_rcp(1.0f + fast_exp2(ir));
    const float t = fmaf(-2.0f, fast_rcp(1.0f + fast_exp2(fmaf(r, ih, sh))), 1.0f);
    const float hn = fmaf(z, hprev - t, t);
    hprev = hn;
    h0 = dpp_f<0x00>(hn);
    h1 = dpp_f<0x55>(hn);
    h2 = dpp_f<0xAA>(hn);
  };

  auto consume_tile = [&](int t) {
    const float* pb = &lds[t & 1][0][row][uc * 3];
    float azv[TT], arv[TT], shv[TT];
#pragma unroll
    for (int k = 0; k < TT; ++k) {           // static indices (rule #20)
      azv[k] = pb[k * 48 + 0];
      arv[k] = pb[k * 48 + 1];
      shv[k] = pb[k * 48 + 2];
    }
#pragma unroll
    for (int k = 0; k < TT; ++k) gate(azv[k], arv[k], shv[k]);
  };

  // ---------------- pipeline ----------------
  if (wid == 0) {
    X0 = pf(0); X1 = pf(1); X2 = pf(2); X3 = pf(3);
    X4 = pf(4); X5 = pf(5); X6 = pf(6); X7 = pf(7);
    prod8(0); prod8(8);                      // tile 0 -> buf 0
  }
  __syncthreads();
  for (int t = 0; t < NT; ++t) {
    if (wid == 0) {
      if (t + 1 < NT) { prod8(TT * (t + 1)); prod8(TT * (t + 1) + 8); }
    } else {
      consume_tile(t);
    }
    __syncthreads();
  }

  // ---------------- epilogue: dense (3->10) + softmax (consumer wave) -----
  if (wid == 1 && l16 < 4) {
    float lg[10];
#pragma unroll
    for (int j = 0; j < 10; ++j)
      lg[j] = dense_b[j] + h0 * dense_w[j] + h1 * dense_w[10 + j] + h2 * dense_w[20 + j];
    float m = lg[0];
#pragma unroll
    for (int j = 1; j < 10; ++j) m = fmaxf(m, lg[j]);
    float e[10];
    float ssum = 0.0f;
#pragma unroll
    for (int j = 0; j < 10; ++j) {
      e[j] = fast_exp2(1.4426950408889634f * (lg[j] - m));
      ssum += e[j];
    }
    const float inv = fast_rcp(ssum);
#pragma unroll
    for (int j = u; j < 10; j += 4) out[(size_t)c * 10 + j] = e[j] * inv;
  }
}

extern "C" void kernel_launch(void* const* d_in, const int* in_sizes, int n_in,
                              void* d_out, int out_size, void* d_ws, size_t ws_size,
                              hipStream_t stream) {
  const float* x      = (const float*)d_in[0];  // [4096,256,64]
  const float* kern   = (const float*)d_in[1];  // [64,9]
  const float* rkern  = (const float*)d_in[2];  // [3,9]
  const float* bias   = (const float*)d_in[3];  // [2,9]
  const float* dw     = (const float*)d_in[4];  // [3,10]
  const float* db     = (const float*)d_in[5];  // [10]
  float* out = (float*)d_out;

  // 4 chains per 128-thread block (2 waves: producer + consumer);
  // 1024 blocks -> 2048 waves -> 2 waves per SIMD chip-wide.
  fused_gru_kernel<<<BB / 4, 128, 0, stream>>>(x, kern, rkern, bias, dw, db, out);
}

// Round 17
// 52.551 us; speedup vs baseline: 1.4758x; 1.2243x over previous
//
#include <hip/hip_runtime.h>

// Problem constants (from reference setup_inputs)
#define BB 4096   // batch
#define SS 256    // sequence length
#define FF 64     // features
#define GG 9      // 3*U gate width

#define NEG_LOG2E -1.4426950408889634f
#define TWO_LOG2E  2.8853900817779268f

typedef float f2 __attribute__((ext_vector_type(2)));

#if __has_builtin(__builtin_amdgcn_exp2f)
__device__ __forceinline__ float fast_exp2(float x) { return __builtin_amdgcn_exp2f(x); }
#else
__device__ __forceinline__ float fast_exp2(float x) { return exp2f(x); }
#endif
#if __has_builtin(__builtin_amdgcn_rcpf)
__device__ __forceinline__ float fast_rcp(float x) { return __builtin_amdgcn_rcpf(x); }
#else
__device__ __forceinline__ float fast_rcp(float x) { return 1.0f / x; }
#endif

// DPP helper: quad_perm (CTRL<0x100) and row ops (row_ror:N = 0x120+N).
template <int CTRL>
__device__ __forceinline__ float dpp_f(float v) {
  return __int_as_float(
      __builtin_amdgcn_mov_dpp(__float_as_int(v), CTRL, 0xF, 0xF, true));
}

// -----------------------------------------------------------------------------
// Fully fused GRU — R17 = R14 champion (54.7us) + final instruction diet.
// Structural search is closed: TLP (R8/R12/R16), reordering (R11), MFMA (R13)
// all lose or tie; only step-instruction removal pays (R14). R17 removes the
// last overhead in the main loop: the per-prefetch clamp (v_cmp+v_cndmask)
// and the final-group redundant loads, by peeling the last 8 steps into a
// load-free epilogue. Main loop: groups 0..30 (steps 0..247) with raw
// prefetch of sg+8..sg+15 (always in range); epilogue: steps 248..255.
// Everything else byte-identical to R14's absmax-0 code.
// -----------------------------------------------------------------------------
__global__ __launch_bounds__(64, 1) void fused_gru_kernel(
    const float* __restrict__ x,           // [B,S,F]
    const float* __restrict__ kernel_w,    // [F,9]
    const float* __restrict__ rec_kernel,  // [3,9]
    const float* __restrict__ bias,        // [2,9]
    const float* __restrict__ dense_w,     // [3,10]
    const float* __restrict__ dense_b,     // [10]
    float* __restrict__ out)               // [B,10]
{
  const int lane = threadIdx.x;        // 0..63
  const int fl   = lane & 15;          // feature-slot within the chain's row
  const int u    = lane & 3;           // gate-unit role within the quad
  const int uc   = (u < 3) ? u : 2;    // lane u==3: clamp unit role (benign)
  const int c    = blockIdx.x * 4 + (lane >> 4);   // chain (batch) id

  // ---- input-projection weights for this lane's 4 features (pre-scaled)
  f2 w01[4], w23[4], w45[4], w67[4];
  float w8[4];
#pragma unroll
  for (int e = 0; e < 4; ++e) {
    const float* kw = kernel_w + (fl * 4 + e) * GG;
    w01[e] = (f2){kw[0] * NEG_LOG2E, kw[1] * NEG_LOG2E};
    w23[e] = (f2){kw[2] * NEG_LOG2E, kw[3] * NEG_LOG2E};
    w45[e] = (f2){kw[4] * NEG_LOG2E, kw[5] * NEG_LOG2E};
    w67[e] = (f2){kw[6] * TWO_LOG2E, kw[7] * TWO_LOG2E};
    w8[e]  = kw[8] * TWO_LOG2E;
  }

  // input bias (+ recurrent bias folded for z/r gates — exact), pre-scaled
  // and SIXTEENTH'd (16-lane reduce restores exactly 1x).
  const float Q = 0.0625f;
  const f2 b01q = {(bias[0] + bias[GG + 0]) * NEG_LOG2E * Q,
                   (bias[1] + bias[GG + 1]) * NEG_LOG2E * Q};
  const f2 b23q = {(bias[2] + bias[GG + 2]) * NEG_LOG2E * Q,
                   (bias[3] + bias[GG + 3]) * NEG_LOG2E * Q};
  const f2 b45q = {(bias[4] + bias[GG + 4]) * NEG_LOG2E * Q,
                   (bias[5] + bias[GG + 5]) * NEG_LOG2E * Q};
  const f2 b67q = {bias[6] * TWO_LOG2E * Q, bias[7] * TWO_LOG2E * Q};
  const float b8q = bias[8] * TWO_LOG2E * Q;

  // recurrent weights for this lane's unit (pre-scaled); only the h-gate's
  // recurrent bias stays separate (it sits inside the r-multiplied term).
  float wz[3], wr[3], wh[3];
#pragma unroll
  for (int hh = 0; hh < 3; ++hh) {
    wz[hh] = rec_kernel[hh * GG + uc]     * NEG_LOG2E;
    wr[hh] = rec_kernel[hh * GG + 3 + uc] * NEG_LOG2E;
    wh[hh] = rec_kernel[hh * GG + 6 + uc] * TWO_LOG2E;
  }
  const float rbh = bias[GG + 6 + uc] * TWO_LOG2E;

  float h0 = 0.0f, h1 = 0.0f, h2 = 0.0f, hprev = 0.0f;

  // per-lane x pointer: row (c,s) = 16 float4s; this lane reads float4 #fl.
  const float4* pc = reinterpret_cast<const float4*>(x) + (size_t)c * SS * 16 + fl;

  // depth-8 register ring (32 VGPRs), named buffers, static indexing
  float4 X0, X1, X2, X3, X4, X5, X6, X7;

  auto step = [&](const float4 v) {
    // projection over this lane's 4 features (20 instrs, f2-packed)
    f2 a01 = b01q, a23 = b23q, a45 = b45q, a67 = b67q;
    float a8 = b8q;
    a01 = v.x * w01[0] + a01; a23 = v.x * w23[0] + a23;
    a45 = v.x * w45[0] + a45; a67 = v.x * w67[0] + a67;
    a8 = fmaf(v.x, w8[0], a8);
    a01 = v.y * w01[1] + a01; a23 = v.y * w23[1] + a23;
    a45 = v.y * w45[1] + a45; a67 = v.y * w67[1] + a67;
    a8 = fmaf(v.y, w8[1], a8);
    a01 = v.z * w01[2] + a01; a23 = v.z * w23[2] + a23;
    a45 = v.z * w45[2] + a45; a67 = v.z * w67[2] + a67;
    a8 = fmaf(v.z, w8[2], a8);
    a01 = v.w * w01[3] + a01; a23 = v.w * w23[3] + a23;
    a45 = v.w * w45[3] + a45; a67 = v.w * w67[3] + a67;
    a8 = fmaf(v.w, w8[3], a8);

    // quad butterfly: after xor1+xor2 every lane holds all 9 quad-sums
    float s0 = a01.x, s1 = a01.y, s2 = a23.x, s3 = a23.y, s4 = a45.x,
          s5 = a45.y, s6 = a67.x, s7 = a67.y, s8 = a8;
    s0 += dpp_f<0xB1>(s0); s1 += dpp_f<0xB1>(s1); s2 += dpp_f<0xB1>(s2);
    s3 += dpp_f<0xB1>(s3); s4 += dpp_f<0xB1>(s4); s5 += dpp_f<0xB1>(s5);
    s6 += dpp_f<0xB1>(s6); s7 += dpp_f<0xB1>(s7); s8 += dpp_f<0xB1>(s8);
    s0 += dpp_f<0x4E>(s0); s1 += dpp_f<0x4E>(s1); s2 += dpp_f<0x4E>(s2);
    s3 += dpp_f<0x4E>(s3); s4 += dpp_f<0x4E>(s4); s5 += dpp_f<0x4E>(s5);
    s6 += dpp_f<0x4E>(s6); s7 += dpp_f<0x4E>(s7); s8 += dpp_f<0x4E>(s8);

    // EARLY role select (3 of 9): ror4/ror8 preserve lane&3 (R12/R14-verified)
    float az = (u == 0) ? s0 : ((u == 1) ? s1 : s2);
    float ar = (u == 0) ? s3 : ((u == 1) ? s4 : s5);
    float sh = (u == 0) ? s6 : ((u == 1) ? s7 : s8);

    // cross-quad rotate-accumulate (direction-free full sum over 4 quads)
    az += dpp_f<0x124>(az); ar += dpp_f<0x124>(ar); sh += dpp_f<0x124>(sh);
    az += dpp_f<0x128>(az); ar += dpp_f<0x128>(ar); sh += dpp_f<0x128>(sh);

    // gate chain (absmax-0 verified math; b0+b1 already inside az/ar)
    const float iz = fmaf(h2, wz[2], fmaf(h1, wz[1], fmaf(h0, wz[0], az)));
    const float ir = fmaf(h2, wr[2], fmaf(h1, wr[1], fmaf(h0, wr[0], ar)));
    const float ih = fmaf(h2, wh[2], fmaf(h1, wh[1], fmaf(h0, wh[0], rbh)));
    const float z = fast_rcp(1.0f + fast_exp2(iz));
    const float r = fast_rcp(1.0f + fast_exp2(ir));
    const float t = fmaf(-2.0f, fast_rcp(1.0f + fast_exp2(fmaf(r, ih, sh))), 1.0f);
    const float hn = fmaf(z, hprev - t, t);
    hprev = hn;
    h0 = dpp_f<0x00>(hn);   // quad_perm [0,0,0,0]
    h1 = dpp_f<0x55>(hn);   // quad_perm [1,1,1,1]
    h2 = dpp_f<0xAA>(hn);   // quad_perm [2,2,2,2]
  };

  auto ld = [&](int sn) -> float4 { return pc[(size_t)sn * 16]; };

  X0 = ld(0); X1 = ld(1); X2 = ld(2); X3 = ld(3);
  X4 = ld(4); X5 = ld(5); X6 = ld(6); X7 = ld(7);

  // main loop: steps 0..247; raw (clamp-free) prefetch of sg+8..sg+15
  for (int sg = 0; sg < SS - 8; sg += 8) {
    step(X0); X0 = ld(sg + 8);
    step(X1); X1 = ld(sg + 9);
    step(X2); X2 = ld(sg + 10);
    step(X3); X3 = ld(sg + 11);
    step(X4); X4 = ld(sg + 12);
    step(X5); X5 = ld(sg + 13);
    step(X6); X6 = ld(sg + 14);
    step(X7); X7 = ld(sg + 15);
  }
  // epilogue: steps 248..255, no loads
  step(X0); step(X1); step(X2); step(X3);
  step(X4); step(X5); step(X6); step(X7);

  // Dense (3 -> 10) + softmax; only quad 0 of each chain row writes.
  if (fl < 4) {
    float lg[10];
#pragma unroll
    for (int j = 0; j < 10; ++j)
      lg[j] = dense_b[j] + h0 * dense_w[j] + h1 * dense_w[10 + j] + h2 * dense_w[20 + j];
    float m = lg[0];
#pragma unroll
    for (int j = 1; j < 10; ++j) m = fmaxf(m, lg[j]);
    float e[10];
    float ssum = 0.0f;
#pragma unroll
    for (int j = 0; j < 10; ++j) {
      e[j] = fast_exp2(1.4426950408889634f * (lg[j] - m));
      ssum += e[j];
    }
    const float inv = fast_rcp(ssum);
#pragma unroll
    for (int j = u; j < 10; j += 4) out[(size_t)c * 10 + j] = e[j] * inv;
  }
}

extern "C" void kernel_launch(void* const* d_in, const int* in_sizes, int n_in,
                              void* d_out, int out_size, void* d_ws, size_t ws_size,
                              hipStream_t stream) {
  const float* x      = (const float*)d_in[0];  // [4096,256,64]
  const float* kern   = (const float*)d_in[1];  // [64,9]
  const float* rkern  = (const float*)d_in[2];  // [3,9]
  const float* bias   = (const float*)d_in[3];  // [2,9]
  const float* dw     = (const float*)d_in[4];  // [3,10]
  const float* db     = (const float*)d_in[5];  // [10]
  float* out = (float*)d_out;

  // 4 chains x 16 lanes per 64-thread block; 1024 blocks -> 1 wave per SIMD
  // on all 1024 SIMDs.
  fused_gru_kernel<<<BB / 4, 64, 0, stream>>>(x, kern, rkern, bias, dw, db, out);
}